// Round 1
// baseline (463.167 us; speedup 1.0000x reference)
//
#include <hip/hip_runtime.h>

// ---------- types ----------
typedef __attribute__((ext_vector_type(8))) short short8;   // 8 bf16 (4 VGPR)
typedef __attribute__((ext_vector_type(4))) float f32x4;    // MFMA accumulator

typedef __attribute__((address_space(1))) const unsigned int guint;
typedef __attribute__((address_space(3))) unsigned int luint;

__device__ __forceinline__ void gload16(const void* g, void* l) {
    __builtin_amdgcn_global_load_lds((guint*)g, (luint*)l, 16, 0, 0);
}

__device__ __forceinline__ unsigned short f2bf(float f) {
    unsigned u = __float_as_uint(f);
    u += 0x7fffu + ((u >> 16) & 1u);   // RNE
    return (unsigned short)(u >> 16);
}

// ---------- prep: x fp32 -> bf16 ----------
__global__ void __launch_bounds__(256) cvt_x_kernel(const float* __restrict__ in,
                                                    unsigned short* __restrict__ out,
                                                    int n8) {
    int stride = gridDim.x * blockDim.x;
    for (int i = blockIdx.x * blockDim.x + threadIdx.x; i < n8; i += stride) {
        const float4* p = reinterpret_cast<const float4*>(in) + (size_t)i * 2;
        float4 a = p[0], b = p[1];
        short8 o;
        o[0] = (short)f2bf(a.x); o[1] = (short)f2bf(a.y);
        o[2] = (short)f2bf(a.z); o[3] = (short)f2bf(a.w);
        o[4] = (short)f2bf(b.x); o[5] = (short)f2bf(b.y);
        o[6] = (short)f2bf(b.z); o[7] = (short)f2bf(b.w);
        *reinterpret_cast<short8*>(out + (size_t)i * 8) = o;
    }
}

// ---------- prep: W (1792x256 f32) -> Wt (256x1792 bf16), transposed ----------
__global__ void __launch_bounds__(256) cvt_wt_kernel(const float* __restrict__ W1,
                                                     const float* __restrict__ W2,
                                                     unsigned short* __restrict__ W1t,
                                                     unsigned short* __restrict__ W2t) {
    const float* W = blockIdx.z ? W2 : W1;
    unsigned short* Wt = blockIdx.z ? W2t : W1t;
    int k0 = blockIdx.x * 64;   // 28 blocks
    int n0 = blockIdx.y * 64;   // 4 blocks
    __shared__ float tile[64][65];
    for (int e = threadIdx.x; e < 4096; e += 256) {
        int r = e >> 6, c = e & 63;
        tile[r][c] = W[(size_t)(k0 + r) * 256 + n0 + c];
    }
    __syncthreads();
    for (int e = threadIdx.x; e < 4096; e += 256) {
        int r = e >> 6, c = e & 63;   // r = n-local, c = k-local
        Wt[(size_t)(n0 + r) * 1792 + k0 + c] = f2bf(tile[c][r]);
    }
}

// ---------- hex conv GEMM ----------
// C[m,n] = leaky( sum_k A[m,k] * W[k,n] + bias[n] (+ resid[m,n]) )
// A[m, j*256+c] = Xg[nbr(m,j), c] (gathered, zero when off-grid)
// MODE 0: out bf16 (h);  MODE 1: out fp32 with residual
template <int MODE>
__global__ void __launch_bounds__(256) hexconv_kernel(
        const unsigned short* __restrict__ xg,     // (B*165, 256) bf16
        const unsigned short* __restrict__ wt,     // (256, 1792) bf16, Wt[n][k]
        const float* __restrict__ bias,            // (256,)
        const float* __restrict__ resid,           // (B*165, 256) fp32 or null
        void* __restrict__ outp,
        const unsigned short* __restrict__ zp)     // 256B zero page
{
    __shared__ unsigned short As[128 * 64];  // As[row][kchunk^ (row&7)] (swizzled content)
    __shared__ unsigned short Bs[128 * 64];  // Bs[n][kchunk ^ (n&7)]

    const int t = threadIdx.x;
    int bid = blockIdx.x;                    // 2640 = 8 * 330
    int swz = (bid & 7) * 330 + (bid >> 3);  // bijective XCD swizzle
    const int mb = swz >> 1, nb = swz & 1;
    const int lane = t & 63, w = t >> 6;
    const int wr = w >> 1, wc = w & 1;

    // ---- staging precompute (constant over K) ----
    int yq[4], xq[4], browq[4], csw[4];
    unsigned short* adst[4];
    unsigned short* bdst[4];
    const unsigned short* wrowp[4];
    const int chunk = t & 7;
#pragma unroll
    for (int q = 0; q < 4; q++) {
        int row = q * 32 + (t >> 3);
        int m = mb * 128 + row;
        int b = m / 165;
        int i = m - b * 165;
        int y = i / 15;
        int x = i - y * 15;
        yq[q] = y; xq[q] = x; browq[q] = m - i;            // b*165
        csw[q] = ((chunk ^ (row & 7)) * 8);                // inverse-swizzled k-chunk (elems)
        adst[q] = As + (q * 256 + t) * 8;                  // linear LDS dest
        bdst[q] = Bs + (q * 256 + t) * 8;
        wrowp[q] = wt + (size_t)(nb * 128 + row) * 1792 + csw[q];
    }

    // ---- fragment ds_read offsets (constant over K) ----
    int offA[4][2], offB[4][2];
    {
        int rA = wr * 64 + (lane & 15);
        int rB = wc * 64 + (lane & 15);
        int r7 = lane & 7;
        int lhi = lane >> 4;
#pragma unroll
        for (int f = 0; f < 4; f++) {
#pragma unroll
            for (int ks = 0; ks < 2; ks++) {
                int gc = ks * 4 + lhi;                      // global k-chunk within BK=64
                offA[f][ks] = (rA + f * 16) * 64 + ((gc ^ r7) * 8);
                offB[f][ks] = (rB + f * 16) * 64 + ((gc ^ r7) * 8);
            }
        }
    }

    f32x4 acc[4][4];
#pragma unroll
    for (int mi = 0; mi < 4; mi++)
#pragma unroll
        for (int ni = 0; ni < 4; ni++) {
            f32x4 z = {0.f, 0.f, 0.f, 0.f};
            acc[mi][ni] = z;
        }

    const int DY[7]  = {-1, -1, 0, 0, 0, 1, 1};
    const int DXO[7] = { 0,  1, -1, 0, 1, 0, 1};   // y (0-based) odd  -> off0
    const int DXE[7] = {-1,  0, -1, 0, 1, -1, 0};  // y (0-based) even -> off1

#pragma unroll 1
    for (int j = 0; j < 7; j++) {
        int aoff[4];
#pragma unroll
        for (int q = 0; q < 4; q++) {
            int dy = DY[j];
            int dx = (yq[q] & 1) ? DXO[j] : DXE[j];
            int ny = yq[q] + dy, nx = xq[q] + dx;
            bool valid = ((unsigned)ny < 11u) && ((unsigned)nx < 15u);
            aoff[q] = valid ? ((browq[q] + ny * 15 + nx) * 256 + csw[q]) : -1;
        }
#pragma unroll 1
        for (int cb = 0; cb < 4; cb++) {
            const int kt = j * 4 + cb;
            // stage A (gathered) + B, linear LDS dest, pre-swizzled global source
#pragma unroll
            for (int q = 0; q < 4; q++) {
                const unsigned short* g = (aoff[q] >= 0) ? (xg + aoff[q] + cb * 64) : zp;
                gload16(g, adst[q]);
            }
#pragma unroll
            for (int q = 0; q < 4; q++) {
                gload16(wrowp[q] + kt * 64, bdst[q]);
            }
            __syncthreads();   // drains vmcnt -> LDS tiles ready
            // compute: 16 ds_read_b128 + 32 MFMA per wave
#pragma unroll
            for (int ks = 0; ks < 2; ks++) {
                short8 av[4], bv[4];
#pragma unroll
                for (int f = 0; f < 4; f++) {
                    av[f] = *reinterpret_cast<const short8*>(&As[offA[f][ks]]);
                    bv[f] = *reinterpret_cast<const short8*>(&Bs[offB[f][ks]]);
                }
#pragma unroll
                for (int mi = 0; mi < 4; mi++)
#pragma unroll
                    for (int ni = 0; ni < 4; ni++)
                        acc[mi][ni] = __builtin_amdgcn_mfma_f32_16x16x32_bf16(
                            av[mi], bv[ni], acc[mi][ni], 0, 0, 0);
            }
            __syncthreads();   // compute done before next-tile overwrite
        }
    }

    // ---- epilogue ----
    const int colBase = nb * 128 + wc * 64 + (lane & 15);
    const int mrow0 = mb * 128 + wr * 64 + ((lane >> 4) * 4);
    if (MODE == 0) {
        unsigned short* outh = (unsigned short*)outp;
#pragma unroll
        for (int ni = 0; ni < 4; ni++) {
            int col = colBase + ni * 16;
            float bb = bias[col];
#pragma unroll
            for (int mi = 0; mi < 4; mi++) {
                int mr = mrow0 + mi * 16;
#pragma unroll
                for (int r = 0; r < 4; r++) {
                    float v = acc[mi][ni][r] + bb;
                    v = v > 0.f ? v : 0.01f * v;
                    outh[(size_t)(mr + r) * 256 + col] = f2bf(v);
                }
            }
        }
    } else {
        float* outf = (float*)outp;
#pragma unroll
        for (int ni = 0; ni < 4; ni++) {
            int col = colBase + ni * 16;
            float bb = bias[col];
#pragma unroll
            for (int mi = 0; mi < 4; mi++) {
                int mr = mrow0 + mi * 16;
#pragma unroll
                for (int r = 0; r < 4; r++) {
                    float v = acc[mi][ni][r] + bb + resid[(size_t)(mr + r) * 256 + col];
                    v = v > 0.f ? v : 0.01f * v;
                    outf[(size_t)(mr + r) * 256 + col] = v;
                }
            }
        }
    }
}

// ---------- launcher ----------
extern "C" void kernel_launch(void* const* d_in, const int* in_sizes, int n_in,
                              void* d_out, int out_size, void* d_ws, size_t ws_size,
                              hipStream_t stream) {
    const float* x  = (const float*)d_in[0];
    const float* W1 = (const float*)d_in[1];
    const float* b1 = (const float*)d_in[2];
    const float* W2 = (const float*)d_in[3];
    const float* b2 = (const float*)d_in[4];
    float* out = (float*)d_out;

    const size_t XBF = (size_t)1024 * 165 * 256 * 2;  // 86,507,520 B
    const size_t WTB = (size_t)256 * 1792 * 2;        //    917,504 B
    char* ws = (char*)d_ws;
    unsigned short* zp  = (unsigned short*)ws;               // 256 B zero page
    unsigned short* xbf = (unsigned short*)(ws + 256);
    unsigned short* hbf = (unsigned short*)(ws + 256 + XBF);
    unsigned short* w1t = (unsigned short*)(ws + 256 + 2 * XBF);
    unsigned short* w2t = (unsigned short*)(ws + 256 + 2 * XBF + WTB);

    hipMemsetAsync(d_ws, 0, 256, stream);
    cvt_x_kernel<<<2048, 256, 0, stream>>>(x, xbf, 5406720);
    cvt_wt_kernel<<<dim3(28, 4, 2), 256, 0, stream>>>(W1, W2, w1t, w2t);
    hexconv_kernel<0><<<2640, 256, 0, stream>>>(xbf, w1t, b1, nullptr, (void*)hbf, zp);
    hexconv_kernel<1><<<2640, 256, 0, stream>>>(hbf, w2t, b2, x, (void*)out, zp);
}

// Round 2
// 450.571 us; speedup vs baseline: 1.0280x; 1.0280x over previous
//
#include <hip/hip_runtime.h>

// ---------- types ----------
typedef __attribute__((ext_vector_type(8))) short short8;   // 8 bf16 (4 VGPR)
typedef __attribute__((ext_vector_type(4))) float f32x4;    // MFMA accumulator

typedef __attribute__((address_space(1))) const unsigned int guint;
typedef __attribute__((address_space(3))) unsigned int luint;

__device__ __forceinline__ void gload16(const void* g, void* l) {
    __builtin_amdgcn_global_load_lds((guint*)g, (luint*)l, 16, 0, 0);
}

__device__ __forceinline__ unsigned short f2bf(float f) {
    unsigned u = __float_as_uint(f);
    u += 0x7fffu + ((u >> 16) & 1u);   // RNE
    return (unsigned short)(u >> 16);
}
__device__ __forceinline__ float bf2f(unsigned short s) {
    return __uint_as_float((unsigned)s << 16);
}

// hex neighbor tables (y is 0-based row inside 11x15 grid)
__device__ const int g_DY[7]  = {-1, -1, 0, 0, 0, 1, 1};
__device__ const int g_DXO[7] = { 0,  1, -1, 0, 1, 0, 1};   // y odd
__device__ const int g_DXE[7] = {-1,  0, -1, 0, 1, -1, 0};  // y even

// ---------- prep: x fp32 -> bf16 ----------
__global__ void __launch_bounds__(256) cvt_x_kernel(const float* __restrict__ in,
                                                    unsigned short* __restrict__ out,
                                                    int n8) {
    int stride = gridDim.x * blockDim.x;
    for (int i = blockIdx.x * blockDim.x + threadIdx.x; i < n8; i += stride) {
        const float4* p = reinterpret_cast<const float4*>(in) + (size_t)i * 2;
        float4 a = p[0], b = p[1];
        short8 o;
        o[0] = (short)f2bf(a.x); o[1] = (short)f2bf(a.y);
        o[2] = (short)f2bf(a.z); o[3] = (short)f2bf(a.w);
        o[4] = (short)f2bf(b.x); o[5] = (short)f2bf(b.y);
        o[6] = (short)f2bf(b.z); o[7] = (short)f2bf(b.w);
        *reinterpret_cast<short8*>(out + (size_t)i * 8) = o;
    }
}

// ---------- prep: W (1792x256 f32) -> Wt (256x1792 bf16), transposed ----------
__global__ void __launch_bounds__(256) cvt_wt_kernel(const float* __restrict__ W1,
                                                     const float* __restrict__ W2,
                                                     unsigned short* __restrict__ W1t,
                                                     unsigned short* __restrict__ W2t) {
    const float* W = blockIdx.z ? W2 : W1;
    unsigned short* Wt = blockIdx.z ? W2t : W1t;
    int k0 = blockIdx.x * 64;
    int n0 = blockIdx.y * 64;
    __shared__ float tile[64][65];
    for (int e = threadIdx.x; e < 4096; e += 256) {
        int r = e >> 6, c = e & 63;
        tile[r][c] = W[(size_t)(k0 + r) * 256 + n0 + c];
    }
    __syncthreads();
    for (int e = threadIdx.x; e < 4096; e += 256) {
        int r = e >> 6, c = e & 63;
        Wt[(size_t)(n0 + r) * 1792 + k0 + c] = f2bf(tile[c][r]);
    }
}

// ---------- 8-phase 256x256 hex-conv GEMM ----------
// C[m,n] = leaky( sum_k A[m,k]*W[k,n] + bias[n] (+ resid) )
// A[m, j*256+c] = Xg[nbr(m,j), c]   (zero off-grid, via zero page)
// MODE 0: out bf16;  MODE 1: out fp32 + bf16 residual
template <int MODE>
__global__ void __launch_bounds__(512, 2) hexconv8_kernel(
        const unsigned short* __restrict__ xg,      // (B*165, 256) bf16
        const unsigned short* __restrict__ wt,      // (256, 1792) bf16 Wt[n][k]
        const float* __restrict__ bias,             // (256,)
        const unsigned short* __restrict__ residbf, // (B*165,256) bf16 or null
        void* __restrict__ outp,
        const unsigned short* __restrict__ zp)      // 256B zero page
{
    // LDS: [buf p][A 256x64 | B 256x64] bf16, double buffered = 128 KiB
    __shared__ unsigned short smem[65536];

    const int t = threadIdx.x;
    const int lane = t & 63, w = t >> 6;
    const int wr = w >> 2, wc = w & 3;   // 2M x 4N waves, per-wave 128x64

    // bijective XCD swizzle for grid 660 (q=82, r=4)
    int bid = blockIdx.x;
    int xcd = bid & 7, idx = bid >> 3;
    const int mb = (xcd < 4 ? xcd * 83 : 332 + (xcd - 4) * 82) + idx;

    // ---- staging precompute (512 thr; each owns 4 A-rows + 4 B-rows) ----
    const int trow = t >> 3;             // 0..63
    const int chunk = t & 7;
    const int aswz = (chunk ^ (trow & 7)) * 8;   // inverse-swizzled 16B chunk (elems)
    int yv[4], xv[4], brow[4], aoff[4];
    const unsigned short* wsrcp[4];
#pragma unroll
    for (int i = 0; i < 4; ++i) {
        int row = i * 64 + trow;                 // tile-local row (A: m-row, B: n-row)
        int m = mb * 256 + row;
        int b = m / 165;
        int ii = m - b * 165;
        int y = ii / 15;
        int x = ii - y * 15;
        yv[i] = y; xv[i] = x; brow[i] = m - ii;  // b*165
        wsrcp[i] = wt + (size_t)row * 1792 + aswz;
    }

#define CALC_AOFF(J) do {                                                     \
        int dy_ = g_DY[J];                                                    \
        int dxo_ = g_DXO[J], dxe_ = g_DXE[J];                                 \
        _Pragma("unroll")                                                     \
        for (int i = 0; i < 4; ++i) {                                         \
            int dx_ = (yv[i] & 1) ? dxo_ : dxe_;                              \
            int ny_ = yv[i] + dy_, nx_ = xv[i] + dx_;                         \
            bool v_ = ((unsigned)ny_ < 11u) && ((unsigned)nx_ < 15u);         \
            aoff[i] = v_ ? ((brow[i] + ny_ * 15 + nx_) * 256 + aswz) : -1;    \
        } } while (0)

    // ---- ds_read fragment offsets (shorts, within one buffer) ----
    int offA[4][2], offB[2][2][2];
    {
        int l15 = lane & 15, lhi = lane >> 4, l7 = lane & 7;
#pragma unroll
        for (int f = 0; f < 4; ++f)
#pragma unroll
            for (int ks = 0; ks < 2; ++ks)
                offA[f][ks] = (wr * 128 + f * 16 + l15) * 64 + (((ks * 4 + lhi) ^ l7) * 8);
#pragma unroll
        for (int nh = 0; nh < 2; ++nh)
#pragma unroll
            for (int g = 0; g < 2; ++g)
#pragma unroll
                for (int ks = 0; ks < 2; ++ks)
                    offB[nh][g][ks] = (wc * 64 + nh * 32 + g * 16 + l15) * 64 +
                                      (((ks * 4 + lhi) ^ l7) * 8);
    }

    f32x4 acc[8][4];
#pragma unroll
    for (int mf = 0; mf < 8; ++mf)
#pragma unroll
        for (int nf = 0; nf < 4; ++nf) {
            f32x4 z = {0.f, 0.f, 0.f, 0.f};
            acc[mf][nf] = z;
        }
    short8 a[4][2], b0[2][2], b1[2][2];

#define STAGE_A(TT, P) do {                                                   \
        int c0_ = ((TT) & 3) * 64;                                            \
        _Pragma("unroll")                                                     \
        for (int i = 0; i < 4; ++i) {                                         \
            const unsigned short* g_ = (aoff[i] >= 0) ? (xg + aoff[i] + c0_) : zp; \
            gload16(g_, &smem[(P) * 32768 + i * 4096 + t * 8]);               \
        } } while (0)
#define STAGE_B(TT, P) do {                                                   \
        int ko_ = (TT) * 64;                                                  \
        _Pragma("unroll")                                                     \
        for (int i = 0; i < 4; ++i)                                           \
            gload16(wsrcp[i] + ko_, &smem[(P) * 32768 + 16384 + i * 4096 + t * 8]); \
        } while (0)

#define LDA(P, MH) do { _Pragma("unroll") for (int f = 0; f < 4; ++f)         \
        _Pragma("unroll") for (int ks = 0; ks < 2; ++ks)                      \
            a[f][ks] = *(const short8*)&smem[(P) * 32768 + (MH) * 4096 + offA[f][ks]]; \
        } while (0)
#define LDB(P, NH, DST) do { _Pragma("unroll") for (int g = 0; g < 2; ++g)    \
        _Pragma("unroll") for (int ks = 0; ks < 2; ++ks)                      \
            DST[g][ks] = *(const short8*)&smem[(P) * 32768 + 16384 + offB[NH][g][ks]]; \
        } while (0)

#define QUAD(MH, NH, BF) do { _Pragma("unroll") for (int f = 0; f < 4; ++f)   \
        _Pragma("unroll") for (int g = 0; g < 2; ++g)                         \
        _Pragma("unroll") for (int ks = 0; ks < 2; ++ks)                      \
            acc[(MH) * 4 + f][(NH) * 2 + g] = __builtin_amdgcn_mfma_f32_16x16x32_bf16( \
                a[f][ks], BF[g][ks], acc[(MH) * 4 + f][(NH) * 2 + g], 0, 0, 0); \
        } while (0)

#define BAR() __builtin_amdgcn_s_barrier()
#define LGKM0() do { asm volatile("s_waitcnt lgkmcnt(0)" ::: "memory");       \
                     __builtin_amdgcn_sched_barrier(0); } while (0)
#define VM0() asm volatile("s_waitcnt vmcnt(0)" ::: "memory")
#define PRIO(N) __builtin_amdgcn_s_setprio(N)

// one K-tile = 4 phases of 16 MFMA; next tile's 8 loads issued in P1/P2,
// single vmcnt(0) at P4 end (~3 phases after issue -> latency covered)
#define TILE(T28, P) do {                                                     \
        int tt_ = (T28) + 1;                                                  \
        /* P1 */                                                              \
        if (tt_ < 28) {                                                       \
            if ((tt_ & 3) == 0) { int jn_ = tt_ >> 2; CALC_AOFF(jn_); }       \
            STAGE_A(tt_, 1 - (P));                                            \
        }                                                                     \
        LDA(P, 0); LDB(P, 0, b0);                                             \
        BAR(); LGKM0(); PRIO(1); QUAD(0, 0, b0); PRIO(0); BAR();              \
        /* P2 */                                                              \
        if (tt_ < 28) STAGE_B(tt_, 1 - (P));                                  \
        LDB(P, 1, b1);                                                        \
        BAR(); LGKM0(); PRIO(1); QUAD(0, 1, b1); PRIO(0); BAR();              \
        /* P3 */                                                              \
        LDA(P, 1);                                                            \
        BAR(); LGKM0(); PRIO(1); QUAD(1, 1, b1); PRIO(0); BAR();              \
        /* P4 */                                                              \
        PRIO(1); QUAD(1, 0, b0); PRIO(0);                                     \
        VM0(); BAR();                                                         \
    } while (0)

    // ---- prologue: stage tile 0, drain, sync ----
    CALC_AOFF(0);
    STAGE_A(0, 0);
    STAGE_B(0, 0);
    VM0(); BAR();

#pragma unroll 1
    for (int it = 0; it < 14; ++it) {
        TILE(2 * it, 0);
        TILE(2 * it + 1, 1);
    }

    // ---- epilogue ----
    const size_t mrowbase = (size_t)mb * 256 + wr * 128;
    const int l15 = lane & 15, lq = (lane >> 4) * 4;
    if (MODE == 0) {
        unsigned short* outh = (unsigned short*)outp;
#pragma unroll
        for (int nf = 0; nf < 4; ++nf) {
            int col = wc * 64 + nf * 16 + l15;
            float bb = bias[col];
#pragma unroll
            for (int mf = 0; mf < 8; ++mf)
#pragma unroll
                for (int r = 0; r < 4; ++r) {
                    size_t mr = mrowbase + mf * 16 + lq + r;
                    float v = acc[mf][nf][r] + bb;
                    v = v > 0.f ? v : 0.01f * v;
                    outh[mr * 256 + col] = f2bf(v);
                }
        }
    } else {
        float* outf = (float*)outp;
#pragma unroll
        for (int nf = 0; nf < 4; ++nf) {
            int col = wc * 64 + nf * 16 + l15;
            float bb = bias[col];
#pragma unroll
            for (int mf = 0; mf < 8; ++mf)
#pragma unroll
                for (int r = 0; r < 4; ++r) {
                    size_t mr = mrowbase + mf * 16 + lq + r;
                    float v = acc[mf][nf][r] + bb + bf2f(residbf[mr * 256 + col]);
                    v = v > 0.f ? v : 0.01f * v;
                    outf[mr * 256 + col] = v;
                }
        }
    }
}

// ---------- launcher ----------
extern "C" void kernel_launch(void* const* d_in, const int* in_sizes, int n_in,
                              void* d_out, int out_size, void* d_ws, size_t ws_size,
                              hipStream_t stream) {
    const float* x  = (const float*)d_in[0];
    const float* W1 = (const float*)d_in[1];
    const float* b1 = (const float*)d_in[2];
    const float* W2 = (const float*)d_in[3];
    const float* b2 = (const float*)d_in[4];
    float* out = (float*)d_out;

    const size_t XBF = (size_t)1024 * 165 * 256 * 2;  // 86,507,520 B
    const size_t WTB = (size_t)256 * 1792 * 2;        //    917,504 B
    char* ws = (char*)d_ws;
    unsigned short* zp  = (unsigned short*)ws;               // 256 B zero page
    unsigned short* xbf = (unsigned short*)(ws + 256);
    unsigned short* hbf = (unsigned short*)(ws + 256 + XBF);
    unsigned short* w1t = (unsigned short*)(ws + 256 + 2 * XBF);
    unsigned short* w2t = (unsigned short*)(ws + 256 + 2 * XBF + WTB);

    hipMemsetAsync(d_ws, 0, 256, stream);
    cvt_x_kernel<<<2048, 256, 0, stream>>>(x, xbf, 5406720);
    cvt_wt_kernel<<<dim3(28, 4, 2), 256, 0, stream>>>(W1, W2, w1t, w2t);
    hexconv8_kernel<0><<<660, 512, 0, stream>>>(xbf, w1t, b1, nullptr, (void*)hbf, zp);
    hexconv8_kernel<1><<<660, 512, 0, stream>>>(hbf, w2t, b2, xbf, (void*)out, zp);
}